// Round 17
// baseline (118.214 us; speedup 1.0000x reference)
//
#include <hip/hip_runtime.h>

#define M_ 4096
#define N_ 131072
#define K_ 6
#define C_ 32
#define MID_ 16
#define CAP_ 320          // bucket capacity per superpoint (mean 192, +9.2 sigma)
#define CNT_STRIDE 16     // one counter per 64B line
#define PB 32             // points per fused block
#define PKS 68            // pkl stride (floats/point), 272B = 16B-aligned

// ---- workspace layout (in floats) ----
#define OFF_AF 0                    // A_f' : M x 16  (BN-folded sp_fea @ wf1^T, +t)
#define OFF_AX (M_*MID_)            // A_x' : M x 16
#define OFF_CB (2*M_*MID_)          // const block
// const-block sub-offsets (floats, relative to OFF_CB); b128-friendly layouts
#define CB_WF1T  0      // [j=16][36]  wf1 scaled, row-per-lane (pad 36)
#define CB_M1PI  576    // [j=16][68]  m1 scaled, pair-interleaved: [j][c*2+s]=m1s[2j+s][c]
#define CB_QFMTT 1664   // [j=16][36]  (wf2^T m2) transposed: [j][q]
#define CB_QXMTT 2240   // [j=16][36]
#define CB_G2PI  2816   // [j=16][68]  G2 pair-interleaved: [j][q*2+s]=G2[q][2j+s]
#define CB_WX1T  3904   // [c=4][16]   wx1 scaled, transposed (c<3 valid)
#define CB_TM    3968   // [32]        folded BN shift for mlp
#define CB_M2TB  4000   // [32]        m2^T m2_b
#define CB_PBFV  4032   // [32]        m2^T wf2_b
#define CB_PBXV  4064   // [32]        m2^T wx2_b
#define CB_UF    4096   // [16][16]    Cholesky U of wf2^T wf2 (upper; zeros below)
#define CB_UX    4352   // [16][16]
#define CB_CF    4608   // [16]        cf = Uf^{-T} (wf2^T wf2_b)
#define CB_CX    4624   // [16]
#define CB_SC    4640   // [0]=rf [1]=rx [2]=|m2_b|^2 [3]=m2_b.wf2_b [4]=m2_b.wx2_b
#define CB_QF0   4648   // [16]        wf2^T m2_b
#define CB_QX0   4664   // [16]
#define CB_N     4680
#define OFF_CNT  (OFF_CB + CB_N + 8)        // M*CNT_STRIDE ints
#define OFF_PAIR (OFF_CNT + M_*CNT_STRIDE)  // M*CAP_ int2 (n, bits(w))

#define BN_EPS 1e-5f

__global__ void prep_kernel(
    const float* __restrict__ sp_fea, const float* __restrict__ sp_xyz,
    const float* __restrict__ wf1_w, const float* __restrict__ wf1_b,
    const float* __restrict__ wf_g, const float* __restrict__ wf_b,
    const float* __restrict__ wf_m, const float* __restrict__ wf_v,
    const float* __restrict__ wf2_w, const float* __restrict__ wf2_b,
    const float* __restrict__ wx1_w, const float* __restrict__ wx1_b,
    const float* __restrict__ wx_g, const float* __restrict__ wx_b,
    const float* __restrict__ wx_m, const float* __restrict__ wx_v,
    const float* __restrict__ wx2_w, const float* __restrict__ wx2_b,
    const float* __restrict__ m1_w, const float* __restrict__ m1_b,
    const float* __restrict__ mb_g, const float* __restrict__ mb_b,
    const float* __restrict__ mb_m, const float* __restrict__ mb_v,
    const float* __restrict__ m2_w, const float* __restrict__ m2_b,
    float* __restrict__ ws)
{
    const int gid = blockIdx.x * blockDim.x + threadIdx.x;

    // zero this superpoint's bucket counter line (replaces hipMemsetAsync)
    if (gid < M_) {
        int4* cz = (int4*)((int*)(ws + OFF_CNT) + gid*CNT_STRIDE);
        const int4 z = make_int4(0, 0, 0, 0);
        cz[0] = z; cz[1] = z; cz[2] = z; cz[3] = z;
    }

    if (gid < M_) {
        float sp[32];
        #pragma unroll
        for (int q = 0; q < 8; ++q) {
            float4 v = *(const float4*)(sp_fea + gid*32 + 4*q);
            sp[4*q] = v.x; sp[4*q+1] = v.y; sp[4*q+2] = v.z; sp[4*q+3] = v.w;
        }
        #pragma unroll
        for (int j = 0; j < 16; ++j) {
            float s = wf_g[j] * rsqrtf(wf_v[j] + BN_EPS);
            float t = s * wf1_b[j] + wf_b[j] - s * wf_m[j];
            float acc = 0.f;
            #pragma unroll
            for (int c = 0; c < 32; ++c) acc += sp[c] * wf1_w[j*32 + c];
            ws[OFF_AF + gid*16 + j] = s * acc + t;
        }
        float sx0 = sp_xyz[gid*3], sx1 = sp_xyz[gid*3+1], sx2 = sp_xyz[gid*3+2];
        #pragma unroll
        for (int j = 0; j < 16; ++j) {
            float s = wx_g[j] * rsqrtf(wx_v[j] + BN_EPS);
            float t = s * wx1_b[j] + wx_b[j] - s * wx_m[j];
            float acc = sx0*wx1_w[j*3] + sx1*wx1_w[j*3+1] + sx2*wx1_w[j*3+2];
            ws[OFF_AX + gid*16 + j] = s * acc + t;
        }
    }

    if (blockIdx.x == 0) {
        __shared__ float sG[512];   // [0..255]=GF, [256..511]=GX
        __shared__ float svv[40];   // [0..15]=vf [16..31]=vx [32]=bbf [33]=bbx
        const int t = threadIdx.x;
        float* cb = ws + OFF_CB;

        // WF1T [j][36] + QFMTT/QXMTT [j][36]
        for (int e = t; e < 512; e += 256) {
            int c = e >> 4, jj = e & 15;
            float s = wf_g[jj] * rsqrtf(wf_v[jj] + BN_EPS);
            cb[CB_WF1T + jj*36 + c] = s * wf1_w[jj*32 + c];
            float aqf = 0.f, aqx = 0.f;   // q = c
            #pragma unroll
            for (int i = 0; i < 32; ++i) {
                aqf += wf2_w[i*16 + jj] * m2_w[i*32 + c];
                aqx += wx2_w[i*16 + jj] * m2_w[i*32 + c];
            }
            cb[CB_QFMTT + jj*36 + c] = aqf;
            cb[CB_QXMTT + jj*36 + c] = aqx;
        }
        if (t < 64) {
            int c = t >> 4, jj = t & 15;
            float s = wx_g[jj] * rsqrtf(wx_v[jj] + BN_EPS);
            cb[CB_WX1T + t] = (c < 3) ? s * wx1_w[jj*3 + c] : 0.f;
        }
        // M1PI [j][c*2+s] + G2PI [j][q*2+s]
        for (int e = t; e < 1024; e += 256) {
            int jj = e >> 6, rem = e & 63, c = rem >> 1, sI = rem & 1;
            int i = 2*jj + sI;
            float s = mb_g[i] * rsqrtf(mb_v[i] + BN_EPS);
            cb[CB_M1PI + jj*68 + c*2 + sI] = s * m1_w[i*32 + c];
            float a = 0.f;
            #pragma unroll
            for (int i2 = 0; i2 < 32; ++i2) a += m2_w[i2*32 + c] * m2_w[i2*32 + i];
            cb[CB_G2PI + jj*68 + c*2 + sI] = a;
        }
        if (t < 32) {
            float s = mb_g[t] * rsqrtf(mb_v[t] + BN_EPS);
            cb[CB_TM + t] = s * m1_b[t] + mb_b[t] - s * mb_m[t];
            float a = 0.f, bf = 0.f, bx = 0.f;
            #pragma unroll
            for (int i2 = 0; i2 < 32; ++i2) {
                a  += m2_w[i2*32 + t] * m2_b[i2];
                bf += m2_w[i2*32 + t] * wf2_b[i2];
                bx += m2_w[i2*32 + t] * wx2_b[i2];
            }
            cb[CB_M2TB + t] = a;
            cb[CB_PBFV + t] = bf;
            cb[CB_PBXV + t] = bx;
        }
        {   // Gram matrices into SHARED (raw G never needed in fused kernel)
            int jj = t >> 4, p = t & 15;
            float accf = 0.f, accx = 0.f;
            #pragma unroll
            for (int i2 = 0; i2 < 32; ++i2) {
                accf += wf2_w[i2*16 + jj] * wf2_w[i2*16 + p];
                accx += wx2_w[i2*16 + jj] * wx2_w[i2*16 + p];
            }
            sG[t]       = accf;
            sG[256 + t] = accx;
        }
        if (t < 16) {
            float q0f = 0.f, q0x = 0.f, vf = 0.f, vx = 0.f;
            #pragma unroll
            for (int i2 = 0; i2 < 32; ++i2) {
                q0f += wf2_w[i2*16 + t] * m2_b[i2];
                q0x += wx2_w[i2*16 + t] * m2_b[i2];
                vf  += wf2_w[i2*16 + t] * wf2_b[i2];
                vx  += wx2_w[i2*16 + t] * wx2_b[i2];
            }
            cb[CB_QF0 + t] = q0f;
            cb[CB_QX0 + t] = q0x;
            svv[t]      = vf;
            svv[16 + t] = vx;
        }
        if (t == 0) {
            float bbf = 0.f, bbx = 0.f, bb2 = 0.f, pcf = 0.f, pcx = 0.f;
            #pragma unroll
            for (int i2 = 0; i2 < 32; ++i2) {
                bbf += wf2_b[i2]*wf2_b[i2];
                bbx += wx2_b[i2]*wx2_b[i2];
                bb2 += m2_b[i2]*m2_b[i2];
                pcf += m2_b[i2]*wf2_b[i2];
                pcx += m2_b[i2]*wx2_b[i2];
            }
            svv[32] = bbf; svv[33] = bbx;
            cb[CB_SC+2] = bb2;
            cb[CB_SC+3] = pcf; cb[CB_SC+4] = pcx;
            cb[CB_SC+5] = 0.f; cb[CB_SC+6] = 0.f; cb[CB_SC+7] = 0.f;
        }
        __syncthreads();

        // ---- cooperative column-Cholesky + triangular solve (wave 0) ----
        if (t < 64) {
            const int lane = t;
            const int half = lane >> 5;          // 0=F, 1=X
            const int p    = lane & 31;
            const bool act = (p < 16);
            const int pp   = p & 15;
            const int sb   = half ? 32 : 0;

            float c[16];
            #pragma unroll
            for (int k = 0; k < 16; ++k)
                c[k] = act ? sG[half*256 + k*16 + pp] : 0.f;

            float u[16];
            #pragma unroll
            for (int k = 0; k < 16; ++k) {
                const float gkk = __shfl(c[k], sb + k);
                const float d = sqrtf(fmaxf(gkk, 1e-30f));
                const float ukp = c[k] / d;
                u[k] = ukp;
                #pragma unroll
                for (int j2 = k + 1; j2 < 16; ++j2)
                    c[j2] -= __shfl(ukp, sb + j2) * ukp;
            }

            const float v = act ? svv[half*16 + pp] : 0.f;
            float acc = 0.f, cf = 0.f;
            #pragma unroll
            for (int i = 0; i < 16; ++i) {
                const float cand = (v - acc) / u[i];
                const float ci = __shfl(cand, sb + i);
                if (pp == i) cf = ci;
                acc += ((i <= pp) ? u[i] : 0.f) * ci;
            }
            float s2 = act ? cf * cf : 0.f;
            s2 += __shfl_xor(s2, 1); s2 += __shfl_xor(s2, 2);
            s2 += __shfl_xor(s2, 4); s2 += __shfl_xor(s2, 8);

            if (act) {
                float* dst = ws + OFF_CB + (half ? CB_UX : CB_UF);
                #pragma unroll
                for (int k = 0; k < 16; ++k)
                    dst[k*16 + pp] = (k <= pp) ? u[k] : 0.f;
                ws[OFF_CB + (half ? CB_CX : CB_CF) + pp] = cf;
                if (pp == 0) ws[OFF_CB + CB_SC + half] = svv[32 + half] - s2;
            }
        }
    }
}

// ---- fused point kernel (R16 structure + VGPR cap 64 via launch_bounds) ----
__global__ __launch_bounds__(256, 8) void fused_kernel(
    const float* __restrict__ o_p_fea, const float* __restrict__ p_xyz,
    const int* __restrict__ idx_abs, float* __restrict__ ws)
{
    __shared__ float cb[CB_N];
    __shared__ float ovl[PB*72];           // phase A: opl[PB*36] | hpb[PB*36]; phase B: pkl
    float* opl = ovl;                      // PB*36 (rows 16B-aligned)
    float* hpb = ovl + PB*36;              // PB*36
    float* pkl = ovl;                      // PB*PKS (68) = 2176 <= 2304

    const int tid = threadIdx.x;
    const int base = blockIdx.x * PB;
    {
        const float* src = ws + OFF_CB;
        for (int i = tid; i < CB_N; i += 256) cb[i] = src[i];
        #pragma unroll
        for (int u = 0; u < 4; ++u) {
            const int idx = tid + u*256;
            opl[(idx >> 5)*36 + (idx & 31)] = o_p_fea[(size_t)base*32 + idx];
        }
    }
    __syncthreads();

    const int g = tid >> 4;
    const int j = tid & 15;
    const int n0 = base + 2*g;
    const int n1 = n0 + 1;

    // ---- phase A1: af, hp for 2 points; b128 reads (5 per c4-iter) ----
    float af0=0.f, af1=0.f, h00=0.f, h01=0.f, h10=0.f, h11=0.f;
    #pragma unroll
    for (int c4 = 0; c4 < 8; ++c4) {
        const float4 w4 = *(const float4*)&cb[CB_WF1T + j*36 + 4*c4];
        const float4 o0 = *(const float4*)&opl[(2*g)*36 + 4*c4];
        const float4 o1 = *(const float4*)&opl[(2*g+1)*36 + 4*c4];
        const float4 ma = *(const float4*)&cb[CB_M1PI + j*68 + 8*c4];      // c,c+1 pairs
        const float4 mb = *(const float4*)&cb[CB_M1PI + j*68 + 8*c4 + 4];  // c+2,c+3 pairs
        af0 += w4.x*o0.x + w4.y*o0.y + w4.z*o0.z + w4.w*o0.w;
        af1 += w4.x*o1.x + w4.y*o1.y + w4.z*o1.z + w4.w*o1.w;
        h00 += ma.x*o0.x + ma.z*o0.y + mb.x*o0.z + mb.z*o0.w;
        h01 += ma.y*o0.x + ma.w*o0.y + mb.y*o0.z + mb.w*o0.w;
        h10 += ma.x*o1.x + ma.z*o1.y + mb.x*o1.z + mb.z*o1.w;
        h11 += ma.y*o1.x + ma.w*o1.y + mb.y*o1.z + mb.w*o1.w;
    }
    {
        const float tm0 = cb[CB_TM + 2*j], tm1 = cb[CB_TM + 2*j + 1];
        h00 = fmaxf(h00 + tm0, 0.f); h01 = fmaxf(h01 + tm1, 0.f);
        h10 = fmaxf(h10 + tm0, 0.f); h11 = fmaxf(h11 + tm1, 0.f);
    }
    const float wx0 = cb[CB_WX1T + j], wx1v = cb[CB_WX1T + 16 + j], wx2v = cb[CB_WX1T + 32 + j];
    const float ax0 = wx0*p_xyz[n0*3] + wx1v*p_xyz[n0*3+1] + wx2v*p_xyz[n0*3+2];
    const float ax1 = wx0*p_xyz[n1*3] + wx1v*p_xyz[n1*3+1] + wx2v*p_xyz[n1*3+2];

    *(float2*)&hpb[(2*g)*36 + 2*j]   = make_float2(h00, h01);
    *(float2*)&hpb[(2*g+1)*36 + 2*j] = make_float2(h10, h11);
    __syncthreads();

    // ---- phase A2: qf/qx + G2 quadratic form; b128 reads (6 per q4-iter) ----
    float qf0 = cb[CB_QF0 + j], qf1 = qf0;
    float qx0 = cb[CB_QX0 + j], qx1 = qx0;
    float t200=0.f, t201=0.f, t210=0.f, t211=0.f;
    #pragma unroll
    for (int q4 = 0; q4 < 8; ++q4) {
        const float4 qf4 = *(const float4*)&cb[CB_QFMTT + j*36 + 4*q4];
        const float4 qx4 = *(const float4*)&cb[CB_QXMTT + j*36 + 4*q4];
        const float4 ga  = *(const float4*)&cb[CB_G2PI + j*68 + 8*q4];      // q,q+1 pairs
        const float4 gb  = *(const float4*)&cb[CB_G2PI + j*68 + 8*q4 + 4];  // q+2,q+3
        const float4 hq0 = *(const float4*)&hpb[(2*g)*36 + 4*q4];
        const float4 hq1 = *(const float4*)&hpb[(2*g+1)*36 + 4*q4];
        qf0 += qf4.x*hq0.x + qf4.y*hq0.y + qf4.z*hq0.z + qf4.w*hq0.w;
        qf1 += qf4.x*hq1.x + qf4.y*hq1.y + qf4.z*hq1.z + qf4.w*hq1.w;
        qx0 += qx4.x*hq0.x + qx4.y*hq0.y + qx4.z*hq0.z + qx4.w*hq0.w;
        qx1 += qx4.x*hq1.x + qx4.y*hq1.y + qx4.z*hq1.z + qx4.w*hq1.w;
        t200 += ga.x*hq0.x + ga.z*hq0.y + gb.x*hq0.z + gb.z*hq0.w;
        t201 += ga.y*hq0.x + ga.w*hq0.y + gb.y*hq0.z + gb.w*hq0.w;
        t210 += ga.x*hq1.x + ga.z*hq1.y + gb.x*hq1.z + gb.z*hq1.w;
        t211 += ga.y*hq1.x + ga.w*hq1.y + gb.y*hq1.z + gb.w*hq1.w;
    }
    const float m2tb0 = 2.f*cb[CB_M2TB + 2*j], m2tb1 = 2.f*cb[CB_M2TB + 2*j + 1];
    const float pbv0 = cb[CB_PBFV + 2*j], pbv1 = cb[CB_PBFV + 2*j + 1];
    const float pxv0 = cb[CB_PBXV + 2*j], pxv1 = cb[CB_PBXV + 2*j + 1];
    float pn20 = h00*(t200 + m2tb0) + h01*(t201 + m2tb1);
    float pn21 = h10*(t210 + m2tb0) + h11*(t211 + m2tb1);
    float pbf0 = h00*pbv0 + h01*pbv1;
    float pbf1 = h10*pbv0 + h11*pbv1;
    float pbx0 = h00*pxv0 + h01*pxv1;
    float pbx1 = h10*pxv0 + h11*pxv1;
    #pragma unroll
    for (int mm = 1; mm < 16; mm <<= 1) {
        pn20 += __shfl_xor(pn20, mm, 16);
        pn21 += __shfl_xor(pn21, mm, 16);
        pbf0 += __shfl_xor(pbf0, mm, 16);
        pbf1 += __shfl_xor(pbf1, mm, 16);
        pbx0 += __shfl_xor(pbx0, mm, 16);
        pbx1 += __shfl_xor(pbx1, mm, 16);
    }
    const float sc2v = cb[CB_SC + 2], sc3v = cb[CB_SC + 3], sc4v = cb[CB_SC + 4];
    const float inv0 = 1.0f / fmaxf(sqrtf(fmaxf(pn20 + sc2v, 0.f)), 1e-12f);
    const float inv1 = 1.0f / fmaxf(sqrtf(fmaxf(pn21 + sc2v, 0.f)), 1e-12f);

    // hpb reads are done; safe to overlay pkl onto opl/hpb after this barrier
    __syncthreads();

    ((float4*)(pkl + (2*g)*PKS))[j]   = make_float4(af0, ax0, qf0*inv0, qx0*inv0);
    ((float4*)(pkl + (2*g+1)*PKS))[j] = make_float4(af1, ax1, qf1*inv1, qx1*inv1);
    if (j == 0) {
        pkl[(2*g)*PKS + 64]   = (pbf0 + sc3v) * inv0;
        pkl[(2*g)*PKS + 65]   = (pbx0 + sc4v) * inv0;
        pkl[(2*g+1)*PKS + 64] = (pbf1 + sc3v) * inv1;
        pkl[(2*g+1)*PKS + 65] = (pbx1 + sc4v) * inv1;
    }
    __syncthreads();

    // ---- phase B: 32 points x 8 k-lanes; Cholesky-form norms ----
    const int slot = tid >> 3;
    const int k    = tid & 7;
    const int n    = base + slot;
    const int kc   = (k < K_) ? k : (K_ - 1);
    const int r    = idx_abs[n * K_ + kc];
    const float* pkb = pkl + slot*PKS;

    float afr[16], axr[16];
    #pragma unroll
    for (int q4 = 0; q4 < 4; ++q4) {
        float4 a = *(const float4*)(ws + OFF_AF + r*16 + 4*q4);
        float4 b = *(const float4*)(ws + OFF_AX + r*16 + 4*q4);
        afr[4*q4] = a.x; afr[4*q4+1] = a.y; afr[4*q4+2] = a.z; afr[4*q4+3] = a.w;
        axr[4*q4] = b.x; axr[4*q4+1] = b.y; axr[4*q4+2] = b.z; axr[4*q4+3] = b.w;
    }

    float hf[16], hx[16];
    float df = 0.f, dx = 0.f;
    #pragma unroll
    for (int jj = 0; jj < 16; ++jj) {
        const float4 v4 = ((const float4*)pkb)[jj];   // (af, ax, qf, qx)
        const float h1 = fmaxf(afr[jj] - v4.x, 0.f);
        const float h2 = fmaxf(axr[jj] - v4.y, 0.f);
        hf[jj] = h1; hx[jj] = h2;
        df += v4.z * h1;
        dx += v4.w * h2;
    }
    const float scbx = pkb[64], scby = pkb[65];

    // nf = rf + || Uf h + cf ||^2  (triangular sweep; zero-prefix chunks skipped)
    float nf = cb[CB_SC + 0], nx = cb[CB_SC + 1];
    #pragma unroll
    for (int q = 0; q < 16; ++q) {
        float yf = cb[CB_CF + q];
        float yx = cb[CB_CX + q];
        #pragma unroll
        for (int p4 = (q >> 2); p4 < 4; ++p4) {
            const float4 uf = *(const float4*)&cb[CB_UF + q*16 + 4*p4];
            const float4 ux = *(const float4*)&cb[CB_UX + q*16 + 4*p4];
            yf += uf.x*hf[4*p4] + uf.y*hf[4*p4+1] + uf.z*hf[4*p4+2] + uf.w*hf[4*p4+3];
            yx += ux.x*hx[4*p4] + ux.y*hx[4*p4+1] + ux.z*hx[4*p4+2] + ux.w*hx[4*p4+3];
        }
        nf += yf * yf;
        nx += yx * yx;
    }
    const float invf = 1.0f / fmaxf(sqrtf(fmaxf(nf, 0.f)), 1e-12f);
    const float invx = 1.0f / fmaxf(sqrtf(fmaxf(nx, 0.f)), 1e-12f);
    float logit = ((df + scbx) * invf) * ((dx + scby) * invx);
    if (k >= K_) logit = -3.0e38f;

    float mx = logit;
    mx = fmaxf(mx, __shfl_xor(mx, 1));
    mx = fmaxf(mx, __shfl_xor(mx, 2));
    mx = fmaxf(mx, __shfl_xor(mx, 4));
    float ex = __expf(logit - mx);
    float s = ex;
    s += __shfl_xor(s, 1);
    s += __shfl_xor(s, 2);
    s += __shfl_xor(s, 4);
    const float w = ex / s;

    if (k < K_) {
        int*  cnt   = (int*)(ws + OFF_CNT);
        int2* pairs = (int2*)(ws + OFF_PAIR);
        const int pos = atomicAdd(&cnt[r*CNT_STRIDE], 1);
        if (pos < CAP_) {
            pairs[(size_t)r*CAP_ + pos] = make_int2(n, __float_as_int(w));
        }
    }
}

// one 256-thread block (4 waves) per superpoint. Pairs staged in LDS, each
// half-wave owns a contiguous chunk, processed unrolled x4 (branch-free
// zero-weight padding) -> 4 independent gathers in flight per half-wave.
__global__ __launch_bounds__(256) void agg_kernel(
    const float* __restrict__ ws,
    const float* __restrict__ o_p_fea, const float* __restrict__ p_xyz,
    float* __restrict__ out)
{
    __shared__ int2 pl[CAP_];
    __shared__ float red[4][40];

    const int tid  = threadIdx.x;
    const int wave = tid >> 6;
    const int lane = tid & 63;
    const int m = blockIdx.x;
    const int eo = lane >> 5;
    const int c  = lane & 31;
    const int hw = wave*2 + eo;          // half-wave id 0..7

    const int*  cnt   = (const int*)(ws + OFF_CNT);
    const int2* pairs = (const int2*)(ws + OFF_PAIR);

    int cn = cnt[m*CNT_STRIDE];
    if (cn > CAP_) cn = CAP_;
    const int2* pb = pairs + (size_t)m * CAP_;

    // stage pairs into LDS (coalesced, contiguous)
    for (int i = tid; i < cn; i += 256) pl[i] = pb[i];
    __syncthreads();

    const int chunk = (cn + 7) >> 3;
    const int s0   = hw * chunk;
    const int epos = min(s0 + chunk, cn);

    float acc = 0.f, wacc = 0.f, xacc = 0.f;
    for (int e = s0; e < epos; e += 4) {
        int   nn[4];
        float wv[4];
        #pragma unroll
        for (int u = 0; u < 4; ++u) {
            if (e + u < epos) {
                const int2 p = pl[e + u];
                nn[u] = p.x;
                wv[u] = __int_as_float(p.y);
            } else {
                nn[u] = 0;
                wv[u] = 0.f;       // zero weight: contribution vanishes
            }
        }
        #pragma unroll
        for (int u = 0; u < 4; ++u) {
            acc += wv[u] * o_p_fea[(size_t)nn[u]*32 + c];
            if (c == 0) wacc += wv[u];
            if (c < 3)  xacc += wv[u] * p_xyz[nn[u]*3 + c];
        }
    }

    acc  += __shfl_xor(acc, 32);
    xacc += __shfl_xor(xacc, 32);
    wacc += __shfl_xor(wacc, 32);
    if (eo == 0) {
        red[wave][c] = acc;
        if (c < 3)  red[wave][33 + c] = xacc;
        if (c == 0) red[wave][36] = wacc;
    }
    __syncthreads();

    if (wave == 0 && eo == 0) {
        const float a = red[0][c] + red[1][c] + red[2][c] + red[3][c];
        const float wtot = red[0][36] + red[1][36] + red[2][36] + red[3][36];
        const float denom = wtot + 1e-8f;
        out[m*32 + c] = a / denom;
        if (c < 3) {
            const float x = red[0][33+c] + red[1][33+c] + red[2][33+c] + red[3][33+c];
            out[M_*C_ + m*3 + c] = x / denom;
        }
    }
}

extern "C" void kernel_launch(void* const* d_in, const int* in_sizes, int n_in,
                              void* d_out, int out_size, void* d_ws, size_t ws_size,
                              hipStream_t stream)
{
    const float* sp_fea  = (const float*)d_in[0];
    const float* sp_xyz  = (const float*)d_in[1];
    const float* o_p_fea = (const float*)d_in[2];
    const float* p_xyz   = (const float*)d_in[3];
    const int*   idx_abs = (const int*)d_in[4];
    const float* wf1_w = (const float*)d_in[8];
    const float* wf1_b = (const float*)d_in[9];
    const float* wf_g  = (const float*)d_in[10];
    const float* wf_b  = (const float*)d_in[11];
    const float* wf_m  = (const float*)d_in[12];
    const float* wf_v  = (const float*)d_in[13];
    const float* wf2_w = (const float*)d_in[14];
    const float* wf2_b = (const float*)d_in[15];
    const float* wx1_w = (const float*)d_in[16];
    const float* wx1_b = (const float*)d_in[17];
    const float* wx_g  = (const float*)d_in[18];
    const float* wx_b  = (const float*)d_in[19];
    const float* wx_m  = (const float*)d_in[20];
    const float* wx_v  = (const float*)d_in[21];
    const float* wx2_w = (const float*)d_in[22];
    const float* wx2_b = (const float*)d_in[23];
    const float* m1_w  = (const float*)d_in[24];
    const float* m1_b  = (const float*)d_in[25];
    const float* mb_g  = (const float*)d_in[26];
    const float* mb_b  = (const float*)d_in[27];
    const float* mb_m  = (const float*)d_in[28];
    const float* mb_v  = (const float*)d_in[29];
    const float* m2_w  = (const float*)d_in[30];
    const float* m2_b  = (const float*)d_in[31];

    float* ws = (float*)d_ws;
    float* out = (float*)d_out;

    prep_kernel<<<16, 256, 0, stream>>>(
        sp_fea, sp_xyz,
        wf1_w, wf1_b, wf_g, wf_b, wf_m, wf_v, wf2_w, wf2_b,
        wx1_w, wx1_b, wx_g, wx_b, wx_m, wx_v, wx2_w, wx2_b,
        m1_w, m1_b, mb_g, mb_b, mb_m, mb_v, m2_w, m2_b,
        ws);

    fused_kernel<<<N_/PB, 256, 0, stream>>>(o_p_fea, p_xyz, idx_abs, ws);

    agg_kernel<<<M_, 256, 0, stream>>>(ws, o_p_fea, p_xyz, out);
}

// Round 18
// 115.555 us; speedup vs baseline: 1.0230x; 1.0230x over previous
//
#include <hip/hip_runtime.h>

#define M_ 4096
#define N_ 131072
#define K_ 6
#define C_ 32
#define MID_ 16
#define CAP_ 320          // bucket capacity per superpoint (mean 192, +9.2 sigma)
#define CNT_STRIDE 16     // one counter per 64B line
#define PB 32             // points per fused block
#define PKS 68            // pkl stride (floats/point), 272B = 16B-aligned

// ---- workspace layout (in floats) ----
#define OFF_AF 0                    // A_f' : M x 16  (BN-folded sp_fea @ wf1^T, +t)
#define OFF_AX (M_*MID_)            // A_x' : M x 16
#define OFF_CB (2*M_*MID_)          // const block
// const-block sub-offsets (floats, relative to OFF_CB); b128-friendly layouts
#define CB_WF1T  0      // [j=16][36]  wf1 scaled, row-per-lane (pad 36)
#define CB_M1PI  576    // [j=16][68]  m1 scaled, pair-interleaved: [j][c*2+s]=m1s[2j+s][c]
#define CB_QFMTT 1664   // [j=16][36]  (wf2^T m2) transposed: [j][q]
#define CB_QXMTT 2240   // [j=16][36]
#define CB_G2PI  2816   // [j=16][68]  G2 pair-interleaved: [j][q*2+s]=G2[q][2j+s]
#define CB_WX1T  3904   // [c=4][16]   wx1 scaled, transposed (c<3 valid)
#define CB_TM    3968   // [32]        folded BN shift for mlp
#define CB_M2TB  4000   // [32]        m2^T m2_b
#define CB_PBFV  4032   // [32]        m2^T wf2_b
#define CB_PBXV  4064   // [32]        m2^T wx2_b
#define CB_UF    4096   // [16][16]    Cholesky U of wf2^T wf2 (upper; zeros below)
#define CB_UX    4352   // [16][16]
#define CB_CF    4608   // [16]        cf = Uf^{-T} (wf2^T wf2_b)
#define CB_CX    4624   // [16]
#define CB_SC    4640   // [0]=rf [1]=rx [2]=|m2_b|^2 [3]=m2_b.wf2_b [4]=m2_b.wx2_b
#define CB_QF0   4648   // [16]        wf2^T m2_b
#define CB_QX0   4664   // [16]
#define CB_N     4680
#define OFF_CNT  (OFF_CB + CB_N + 8)        // M*CNT_STRIDE ints
#define OFF_PAIR (OFF_CNT + M_*CNT_STRIDE)  // M*CAP_ int2 (n, bits(w))

#define BN_EPS 1e-5f

__global__ void prep_kernel(
    const float* __restrict__ sp_fea, const float* __restrict__ sp_xyz,
    const float* __restrict__ wf1_w, const float* __restrict__ wf1_b,
    const float* __restrict__ wf_g, const float* __restrict__ wf_b,
    const float* __restrict__ wf_m, const float* __restrict__ wf_v,
    const float* __restrict__ wf2_w, const float* __restrict__ wf2_b,
    const float* __restrict__ wx1_w, const float* __restrict__ wx1_b,
    const float* __restrict__ wx_g, const float* __restrict__ wx_b,
    const float* __restrict__ wx_m, const float* __restrict__ wx_v,
    const float* __restrict__ wx2_w, const float* __restrict__ wx2_b,
    const float* __restrict__ m1_w, const float* __restrict__ m1_b,
    const float* __restrict__ mb_g, const float* __restrict__ mb_b,
    const float* __restrict__ mb_m, const float* __restrict__ mb_v,
    const float* __restrict__ m2_w, const float* __restrict__ m2_b,
    float* __restrict__ ws)
{
    const int gid = blockIdx.x * blockDim.x + threadIdx.x;

    // zero this superpoint's bucket counter line (replaces hipMemsetAsync)
    if (gid < M_) {
        int4* cz = (int4*)((int*)(ws + OFF_CNT) + gid*CNT_STRIDE);
        const int4 z = make_int4(0, 0, 0, 0);
        cz[0] = z; cz[1] = z; cz[2] = z; cz[3] = z;
    }

    if (gid < M_) {
        float sp[32];
        #pragma unroll
        for (int q = 0; q < 8; ++q) {
            float4 v = *(const float4*)(sp_fea + gid*32 + 4*q);
            sp[4*q] = v.x; sp[4*q+1] = v.y; sp[4*q+2] = v.z; sp[4*q+3] = v.w;
        }
        #pragma unroll
        for (int j = 0; j < 16; ++j) {
            float s = wf_g[j] * rsqrtf(wf_v[j] + BN_EPS);
            float t = s * wf1_b[j] + wf_b[j] - s * wf_m[j];
            float acc = 0.f;
            #pragma unroll
            for (int c = 0; c < 32; ++c) acc += sp[c] * wf1_w[j*32 + c];
            ws[OFF_AF + gid*16 + j] = s * acc + t;
        }
        float sx0 = sp_xyz[gid*3], sx1 = sp_xyz[gid*3+1], sx2 = sp_xyz[gid*3+2];
        #pragma unroll
        for (int j = 0; j < 16; ++j) {
            float s = wx_g[j] * rsqrtf(wx_v[j] + BN_EPS);
            float t = s * wx1_b[j] + wx_b[j] - s * wx_m[j];
            float acc = sx0*wx1_w[j*3] + sx1*wx1_w[j*3+1] + sx2*wx1_w[j*3+2];
            ws[OFF_AX + gid*16 + j] = s * acc + t;
        }
    }

    if (blockIdx.x == 0) {
        __shared__ float sG[512];   // [0..255]=GF, [256..511]=GX
        __shared__ float svv[40];   // [0..15]=vf [16..31]=vx [32]=bbf [33]=bbx
        const int t = threadIdx.x;
        float* cb = ws + OFF_CB;

        // WF1T [j][36] + QFMTT/QXMTT [j][36]
        for (int e = t; e < 512; e += 256) {
            int c = e >> 4, jj = e & 15;
            float s = wf_g[jj] * rsqrtf(wf_v[jj] + BN_EPS);
            cb[CB_WF1T + jj*36 + c] = s * wf1_w[jj*32 + c];
            float aqf = 0.f, aqx = 0.f;   // q = c
            #pragma unroll
            for (int i = 0; i < 32; ++i) {
                aqf += wf2_w[i*16 + jj] * m2_w[i*32 + c];
                aqx += wx2_w[i*16 + jj] * m2_w[i*32 + c];
            }
            cb[CB_QFMTT + jj*36 + c] = aqf;
            cb[CB_QXMTT + jj*36 + c] = aqx;
        }
        if (t < 64) {
            int c = t >> 4, jj = t & 15;
            float s = wx_g[jj] * rsqrtf(wx_v[jj] + BN_EPS);
            cb[CB_WX1T + t] = (c < 3) ? s * wx1_w[jj*3 + c] : 0.f;
        }
        // M1PI [j][c*2+s] + G2PI [j][q*2+s]
        for (int e = t; e < 1024; e += 256) {
            int jj = e >> 6, rem = e & 63, c = rem >> 1, sI = rem & 1;
            int i = 2*jj + sI;
            float s = mb_g[i] * rsqrtf(mb_v[i] + BN_EPS);
            cb[CB_M1PI + jj*68 + c*2 + sI] = s * m1_w[i*32 + c];
            float a = 0.f;
            #pragma unroll
            for (int i2 = 0; i2 < 32; ++i2) a += m2_w[i2*32 + c] * m2_w[i2*32 + i];
            cb[CB_G2PI + jj*68 + c*2 + sI] = a;
        }
        if (t < 32) {
            float s = mb_g[t] * rsqrtf(mb_v[t] + BN_EPS);
            cb[CB_TM + t] = s * m1_b[t] + mb_b[t] - s * mb_m[t];
            float a = 0.f, bf = 0.f, bx = 0.f;
            #pragma unroll
            for (int i2 = 0; i2 < 32; ++i2) {
                a  += m2_w[i2*32 + t] * m2_b[i2];
                bf += m2_w[i2*32 + t] * wf2_b[i2];
                bx += m2_w[i2*32 + t] * wx2_b[i2];
            }
            cb[CB_M2TB + t] = a;
            cb[CB_PBFV + t] = bf;
            cb[CB_PBXV + t] = bx;
        }
        {   // Gram matrices into SHARED (raw G never needed in fused kernel)
            int jj = t >> 4, p = t & 15;
            float accf = 0.f, accx = 0.f;
            #pragma unroll
            for (int i2 = 0; i2 < 32; ++i2) {
                accf += wf2_w[i2*16 + jj] * wf2_w[i2*16 + p];
                accx += wx2_w[i2*16 + jj] * wx2_w[i2*16 + p];
            }
            sG[t]       = accf;
            sG[256 + t] = accx;
        }
        if (t < 16) {
            float q0f = 0.f, q0x = 0.f, vf = 0.f, vx = 0.f;
            #pragma unroll
            for (int i2 = 0; i2 < 32; ++i2) {
                q0f += wf2_w[i2*16 + t] * m2_b[i2];
                q0x += wx2_w[i2*16 + t] * m2_b[i2];
                vf  += wf2_w[i2*16 + t] * wf2_b[i2];
                vx  += wx2_w[i2*16 + t] * wx2_b[i2];
            }
            cb[CB_QF0 + t] = q0f;
            cb[CB_QX0 + t] = q0x;
            svv[t]      = vf;
            svv[16 + t] = vx;
        }
        if (t == 0) {
            float bbf = 0.f, bbx = 0.f, bb2 = 0.f, pcf = 0.f, pcx = 0.f;
            #pragma unroll
            for (int i2 = 0; i2 < 32; ++i2) {
                bbf += wf2_b[i2]*wf2_b[i2];
                bbx += wx2_b[i2]*wx2_b[i2];
                bb2 += m2_b[i2]*m2_b[i2];
                pcf += m2_b[i2]*wf2_b[i2];
                pcx += m2_b[i2]*wx2_b[i2];
            }
            svv[32] = bbf; svv[33] = bbx;
            cb[CB_SC+2] = bb2;
            cb[CB_SC+3] = pcf; cb[CB_SC+4] = pcx;
            cb[CB_SC+5] = 0.f; cb[CB_SC+6] = 0.f; cb[CB_SC+7] = 0.f;
        }
        __syncthreads();

        // ---- cooperative column-Cholesky + triangular solve (wave 0) ----
        if (t < 64) {
            const int lane = t;
            const int half = lane >> 5;          // 0=F, 1=X
            const int p    = lane & 31;
            const bool act = (p < 16);
            const int pp   = p & 15;
            const int sb   = half ? 32 : 0;

            float c[16];
            #pragma unroll
            for (int k = 0; k < 16; ++k)
                c[k] = act ? sG[half*256 + k*16 + pp] : 0.f;

            float u[16];
            #pragma unroll
            for (int k = 0; k < 16; ++k) {
                const float gkk = __shfl(c[k], sb + k);
                const float d = sqrtf(fmaxf(gkk, 1e-30f));
                const float ukp = c[k] / d;
                u[k] = ukp;
                #pragma unroll
                for (int j2 = k + 1; j2 < 16; ++j2)
                    c[j2] -= __shfl(ukp, sb + j2) * ukp;
            }

            const float v = act ? svv[half*16 + pp] : 0.f;
            float acc = 0.f, cf = 0.f;
            #pragma unroll
            for (int i = 0; i < 16; ++i) {
                const float cand = (v - acc) / u[i];
                const float ci = __shfl(cand, sb + i);
                if (pp == i) cf = ci;
                acc += ((i <= pp) ? u[i] : 0.f) * ci;
            }
            float s2 = act ? cf * cf : 0.f;
            s2 += __shfl_xor(s2, 1); s2 += __shfl_xor(s2, 2);
            s2 += __shfl_xor(s2, 4); s2 += __shfl_xor(s2, 8);

            if (act) {
                float* dst = ws + OFF_CB + (half ? CB_UX : CB_UF);
                #pragma unroll
                for (int k = 0; k < 16; ++k)
                    dst[k*16 + pp] = (k <= pp) ? u[k] : 0.f;
                ws[OFF_CB + (half ? CB_CX : CB_CF) + pp] = cf;
                if (pp == 0) ws[OFF_CB + CB_SC + half] = svv[32 + half] - s2;
            }
        }
    }
}

// ---- fused point kernel (R16 structure): 32 points/block; phase A (16x16 coop,
// ---- 2 pts/group, b128 LDS) -> LDS pack (overlaid) -> phase B -> scatter
__global__ __launch_bounds__(256) void fused_kernel(
    const float* __restrict__ o_p_fea, const float* __restrict__ p_xyz,
    const int* __restrict__ idx_abs, float* __restrict__ ws)
{
    __shared__ float cb[CB_N];
    __shared__ float ovl[PB*72];           // phase A: opl[PB*36] | hpb[PB*36]; phase B: pkl
    float* opl = ovl;                      // PB*36 (rows 16B-aligned)
    float* hpb = ovl + PB*36;              // PB*36
    float* pkl = ovl;                      // PB*PKS (68) = 2176 <= 2304

    const int tid = threadIdx.x;
    const int base = blockIdx.x * PB;
    {
        const float* src = ws + OFF_CB;
        for (int i = tid; i < CB_N; i += 256) cb[i] = src[i];
        #pragma unroll
        for (int u = 0; u < 4; ++u) {
            const int idx = tid + u*256;
            opl[(idx >> 5)*36 + (idx & 31)] = o_p_fea[(size_t)base*32 + idx];
        }
    }
    __syncthreads();

    const int g = tid >> 4;
    const int j = tid & 15;
    const int n0 = base + 2*g;
    const int n1 = n0 + 1;

    // ---- phase A1: af, hp for 2 points; b128 reads (5 per c4-iter) ----
    float af0=0.f, af1=0.f, h00=0.f, h01=0.f, h10=0.f, h11=0.f;
    #pragma unroll
    for (int c4 = 0; c4 < 8; ++c4) {
        const float4 w4 = *(const float4*)&cb[CB_WF1T + j*36 + 4*c4];
        const float4 o0 = *(const float4*)&opl[(2*g)*36 + 4*c4];
        const float4 o1 = *(const float4*)&opl[(2*g+1)*36 + 4*c4];
        const float4 ma = *(const float4*)&cb[CB_M1PI + j*68 + 8*c4];      // c,c+1 pairs
        const float4 mb = *(const float4*)&cb[CB_M1PI + j*68 + 8*c4 + 4];  // c+2,c+3 pairs
        af0 += w4.x*o0.x + w4.y*o0.y + w4.z*o0.z + w4.w*o0.w;
        af1 += w4.x*o1.x + w4.y*o1.y + w4.z*o1.z + w4.w*o1.w;
        h00 += ma.x*o0.x + ma.z*o0.y + mb.x*o0.z + mb.z*o0.w;
        h01 += ma.y*o0.x + ma.w*o0.y + mb.y*o0.z + mb.w*o0.w;
        h10 += ma.x*o1.x + ma.z*o1.y + mb.x*o1.z + mb.z*o1.w;
        h11 += ma.y*o1.x + ma.w*o1.y + mb.y*o1.z + mb.w*o1.w;
    }
    {
        const float tm0 = cb[CB_TM + 2*j], tm1 = cb[CB_TM + 2*j + 1];
        h00 = fmaxf(h00 + tm0, 0.f); h01 = fmaxf(h01 + tm1, 0.f);
        h10 = fmaxf(h10 + tm0, 0.f); h11 = fmaxf(h11 + tm1, 0.f);
    }
    const float wx0 = cb[CB_WX1T + j], wx1v = cb[CB_WX1T + 16 + j], wx2v = cb[CB_WX1T + 32 + j];
    const float ax0 = wx0*p_xyz[n0*3] + wx1v*p_xyz[n0*3+1] + wx2v*p_xyz[n0*3+2];
    const float ax1 = wx0*p_xyz[n1*3] + wx1v*p_xyz[n1*3+1] + wx2v*p_xyz[n1*3+2];

    *(float2*)&hpb[(2*g)*36 + 2*j]   = make_float2(h00, h01);
    *(float2*)&hpb[(2*g+1)*36 + 2*j] = make_float2(h10, h11);
    __syncthreads();

    // ---- phase A2: qf/qx + G2 quadratic form; b128 reads (6 per q4-iter) ----
    float qf0 = cb[CB_QF0 + j], qf1 = qf0;
    float qx0 = cb[CB_QX0 + j], qx1 = qx0;
    float t200=0.f, t201=0.f, t210=0.f, t211=0.f;
    #pragma unroll
    for (int q4 = 0; q4 < 8; ++q4) {
        const float4 qf4 = *(const float4*)&cb[CB_QFMTT + j*36 + 4*q4];
        const float4 qx4 = *(const float4*)&cb[CB_QXMTT + j*36 + 4*q4];
        const float4 ga  = *(const float4*)&cb[CB_G2PI + j*68 + 8*q4];      // q,q+1 pairs
        const float4 gb  = *(const float4*)&cb[CB_G2PI + j*68 + 8*q4 + 4];  // q+2,q+3
        const float4 hq0 = *(const float4*)&hpb[(2*g)*36 + 4*q4];
        const float4 hq1 = *(const float4*)&hpb[(2*g+1)*36 + 4*q4];
        qf0 += qf4.x*hq0.x + qf4.y*hq0.y + qf4.z*hq0.z + qf4.w*hq0.w;
        qf1 += qf4.x*hq1.x + qf4.y*hq1.y + qf4.z*hq1.z + qf4.w*hq1.w;
        qx0 += qx4.x*hq0.x + qx4.y*hq0.y + qx4.z*hq0.z + qx4.w*hq0.w;
        qx1 += qx4.x*hq1.x + qx4.y*hq1.y + qx4.z*hq1.z + qx4.w*hq1.w;
        t200 += ga.x*hq0.x + ga.z*hq0.y + gb.x*hq0.z + gb.z*hq0.w;
        t201 += ga.y*hq0.x + ga.w*hq0.y + gb.y*hq0.z + gb.w*hq0.w;
        t210 += ga.x*hq1.x + ga.z*hq1.y + gb.x*hq1.z + gb.z*hq1.w;
        t211 += ga.y*hq1.x + ga.w*hq1.y + gb.y*hq1.z + gb.w*hq1.w;
    }
    const float m2tb0 = 2.f*cb[CB_M2TB + 2*j], m2tb1 = 2.f*cb[CB_M2TB + 2*j + 1];
    const float pbv0 = cb[CB_PBFV + 2*j], pbv1 = cb[CB_PBFV + 2*j + 1];
    const float pxv0 = cb[CB_PBXV + 2*j], pxv1 = cb[CB_PBXV + 2*j + 1];
    float pn20 = h00*(t200 + m2tb0) + h01*(t201 + m2tb1);
    float pn21 = h10*(t210 + m2tb0) + h11*(t211 + m2tb1);
    float pbf0 = h00*pbv0 + h01*pbv1;
    float pbf1 = h10*pbv0 + h11*pbv1;
    float pbx0 = h00*pxv0 + h01*pxv1;
    float pbx1 = h10*pxv0 + h11*pxv1;
    #pragma unroll
    for (int mm = 1; mm < 16; mm <<= 1) {
        pn20 += __shfl_xor(pn20, mm, 16);
        pn21 += __shfl_xor(pn21, mm, 16);
        pbf0 += __shfl_xor(pbf0, mm, 16);
        pbf1 += __shfl_xor(pbf1, mm, 16);
        pbx0 += __shfl_xor(pbx0, mm, 16);
        pbx1 += __shfl_xor(pbx1, mm, 16);
    }
    const float sc2v = cb[CB_SC + 2], sc3v = cb[CB_SC + 3], sc4v = cb[CB_SC + 4];
    const float inv0 = 1.0f / fmaxf(sqrtf(fmaxf(pn20 + sc2v, 0.f)), 1e-12f);
    const float inv1 = 1.0f / fmaxf(sqrtf(fmaxf(pn21 + sc2v, 0.f)), 1e-12f);

    // hpb reads are done; safe to overlay pkl onto opl/hpb after this barrier
    __syncthreads();

    ((float4*)(pkl + (2*g)*PKS))[j]   = make_float4(af0, ax0, qf0*inv0, qx0*inv0);
    ((float4*)(pkl + (2*g+1)*PKS))[j] = make_float4(af1, ax1, qf1*inv1, qx1*inv1);
    if (j == 0) {
        pkl[(2*g)*PKS + 64]   = (pbf0 + sc3v) * inv0;
        pkl[(2*g)*PKS + 65]   = (pbx0 + sc4v) * inv0;
        pkl[(2*g+1)*PKS + 64] = (pbf1 + sc3v) * inv1;
        pkl[(2*g+1)*PKS + 65] = (pbx1 + sc4v) * inv1;
    }
    __syncthreads();

    // ---- phase B: 32 points x 8 k-lanes; Cholesky-form norms ----
    const int slot = tid >> 3;
    const int k    = tid & 7;
    const int n    = base + slot;
    const int kc   = (k < K_) ? k : (K_ - 1);
    const int r    = idx_abs[n * K_ + kc];
    const float* pkb = pkl + slot*PKS;

    float afr[16], axr[16];
    #pragma unroll
    for (int q4 = 0; q4 < 4; ++q4) {
        float4 a = *(const float4*)(ws + OFF_AF + r*16 + 4*q4);
        float4 b = *(const float4*)(ws + OFF_AX + r*16 + 4*q4);
        afr[4*q4] = a.x; afr[4*q4+1] = a.y; afr[4*q4+2] = a.z; afr[4*q4+3] = a.w;
        axr[4*q4] = b.x; axr[4*q4+1] = b.y; axr[4*q4+2] = b.z; axr[4*q4+3] = b.w;
    }

    float hf[16], hx[16];
    float df = 0.f, dx = 0.f;
    #pragma unroll
    for (int jj = 0; jj < 16; ++jj) {
        const float4 v4 = ((const float4*)pkb)[jj];   // (af, ax, qf, qx)
        const float h1 = fmaxf(afr[jj] - v4.x, 0.f);
        const float h2 = fmaxf(axr[jj] - v4.y, 0.f);
        hf[jj] = h1; hx[jj] = h2;
        df += v4.z * h1;
        dx += v4.w * h2;
    }
    const float scbx = pkb[64], scby = pkb[65];

    // nf = rf + || Uf h + cf ||^2  (triangular sweep; zero-prefix chunks skipped)
    float nf = cb[CB_SC + 0], nx = cb[CB_SC + 1];
    #pragma unroll
    for (int q = 0; q < 16; ++q) {
        float yf = cb[CB_CF + q];
        float yx = cb[CB_CX + q];
        #pragma unroll
        for (int p4 = (q >> 2); p4 < 4; ++p4) {
            const float4 uf = *(const float4*)&cb[CB_UF + q*16 + 4*p4];
            const float4 ux = *(const float4*)&cb[CB_UX + q*16 + 4*p4];
            yf += uf.x*hf[4*p4] + uf.y*hf[4*p4+1] + uf.z*hf[4*p4+2] + uf.w*hf[4*p4+3];
            yx += ux.x*hx[4*p4] + ux.y*hx[4*p4+1] + ux.z*hx[4*p4+2] + ux.w*hx[4*p4+3];
        }
        nf += yf * yf;
        nx += yx * yx;
    }
    const float invf = 1.0f / fmaxf(sqrtf(fmaxf(nf, 0.f)), 1e-12f);
    const float invx = 1.0f / fmaxf(sqrtf(fmaxf(nx, 0.f)), 1e-12f);
    float logit = ((df + scbx) * invf) * ((dx + scby) * invx);
    if (k >= K_) logit = -3.0e38f;

    float mx = logit;
    mx = fmaxf(mx, __shfl_xor(mx, 1));
    mx = fmaxf(mx, __shfl_xor(mx, 2));
    mx = fmaxf(mx, __shfl_xor(mx, 4));
    float ex = __expf(logit - mx);
    float s = ex;
    s += __shfl_xor(s, 1);
    s += __shfl_xor(s, 2);
    s += __shfl_xor(s, 4);
    const float w = ex / s;

    if (k < K_) {
        int*  cnt   = (int*)(ws + OFF_CNT);
        int2* pairs = (int2*)(ws + OFF_PAIR);
        const int pos = atomicAdd(&cnt[r*CNT_STRIDE], 1);
        if (pos < CAP_) {
            pairs[(size_t)r*CAP_ + pos] = make_int2(n, __float_as_int(w));
        }
    }
}

// one 256-thread block (4 waves) per superpoint. Pairs staged in LDS, each
// half-wave owns a contiguous chunk, processed unrolled x4 (branch-free
// zero-weight padding) -> 4 independent gathers in flight per half-wave.
__global__ __launch_bounds__(256) void agg_kernel(
    const float* __restrict__ ws,
    const float* __restrict__ o_p_fea, const float* __restrict__ p_xyz,
    float* __restrict__ out)
{
    __shared__ int2 pl[CAP_];
    __shared__ float red[4][40];

    const int tid  = threadIdx.x;
    const int wave = tid >> 6;
    const int lane = tid & 63;
    const int m = blockIdx.x;
    const int eo = lane >> 5;
    const int c  = lane & 31;
    const int hw = wave*2 + eo;          // half-wave id 0..7

    const int*  cnt   = (const int*)(ws + OFF_CNT);
    const int2* pairs = (const int2*)(ws + OFF_PAIR);

    int cn = cnt[m*CNT_STRIDE];
    if (cn > CAP_) cn = CAP_;
    const int2* pb = pairs + (size_t)m * CAP_;

    // stage pairs into LDS (coalesced, contiguous)
    for (int i = tid; i < cn; i += 256) pl[i] = pb[i];
    __syncthreads();

    const int chunk = (cn + 7) >> 3;
    const int s0   = hw * chunk;
    const int epos = min(s0 + chunk, cn);

    float acc = 0.f, wacc = 0.f, xacc = 0.f;
    for (int e = s0; e < epos; e += 4) {
        int   nn[4];
        float wv[4];
        #pragma unroll
        for (int u = 0; u < 4; ++u) {
            if (e + u < epos) {
                const int2 p = pl[e + u];
                nn[u] = p.x;
                wv[u] = __int_as_float(p.y);
            } else {
                nn[u] = 0;
                wv[u] = 0.f;       // zero weight: contribution vanishes
            }
        }
        #pragma unroll
        for (int u = 0; u < 4; ++u) {
            acc += wv[u] * o_p_fea[(size_t)nn[u]*32 + c];
            if (c == 0) wacc += wv[u];
            if (c < 3)  xacc += wv[u] * p_xyz[nn[u]*3 + c];
        }
    }

    acc  += __shfl_xor(acc, 32);
    xacc += __shfl_xor(xacc, 32);
    wacc += __shfl_xor(wacc, 32);
    if (eo == 0) {
        red[wave][c] = acc;
        if (c < 3)  red[wave][33 + c] = xacc;
        if (c == 0) red[wave][36] = wacc;
    }
    __syncthreads();

    if (wave == 0 && eo == 0) {
        const float a = red[0][c] + red[1][c] + red[2][c] + red[3][c];
        const float wtot = red[0][36] + red[1][36] + red[2][36] + red[3][36];
        const float denom = wtot + 1e-8f;
        out[m*32 + c] = a / denom;
        if (c < 3) {
            const float x = red[0][33+c] + red[1][33+c] + red[2][33+c] + red[3][33+c];
            out[M_*C_ + m*3 + c] = x / denom;
        }
    }
}

extern "C" void kernel_launch(void* const* d_in, const int* in_sizes, int n_in,
                              void* d_out, int out_size, void* d_ws, size_t ws_size,
                              hipStream_t stream)
{
    const float* sp_fea  = (const float*)d_in[0];
    const float* sp_xyz  = (const float*)d_in[1];
    const float* o_p_fea = (const float*)d_in[2];
    const float* p_xyz   = (const float*)d_in[3];
    const int*   idx_abs = (const int*)d_in[4];
    const float* wf1_w = (const float*)d_in[8];
    const float* wf1_b = (const float*)d_in[9];
    const float* wf_g  = (const float*)d_in[10];
    const float* wf_b  = (const float*)d_in[11];
    const float* wf_m  = (const float*)d_in[12];
    const float* wf_v  = (const float*)d_in[13];
    const float* wf2_w = (const float*)d_in[14];
    const float* wf2_b = (const float*)d_in[15];
    const float* wx1_w = (const float*)d_in[16];
    const float* wx1_b = (const float*)d_in[17];
    const float* wx_g  = (const float*)d_in[18];
    const float* wx_b  = (const float*)d_in[19];
    const float* wx_m  = (const float*)d_in[20];
    const float* wx_v  = (const float*)d_in[21];
    const float* wx2_w = (const float*)d_in[22];
    const float* wx2_b = (const float*)d_in[23];
    const float* m1_w  = (const float*)d_in[24];
    const float* m1_b  = (const float*)d_in[25];
    const float* mb_g  = (const float*)d_in[26];
    const float* mb_b  = (const float*)d_in[27];
    const float* mb_m  = (const float*)d_in[28];
    const float* mb_v  = (const float*)d_in[29];
    const float* m2_w  = (const float*)d_in[30];
    const float* m2_b  = (const float*)d_in[31];

    float* ws = (float*)d_ws;
    float* out = (float*)d_out;

    prep_kernel<<<16, 256, 0, stream>>>(
        sp_fea, sp_xyz,
        wf1_w, wf1_b, wf_g, wf_b, wf_m, wf_v, wf2_w, wf2_b,
        wx1_w, wx1_b, wx_g, wx_b, wx_m, wx_v, wx2_w, wx2_b,
        m1_w, m1_b, mb_g, mb_b, mb_m, mb_v, m2_w, m2_b,
        ws);

    fused_kernel<<<N_/PB, 256, 0, stream>>>(o_p_fea, p_xyz, idx_abs, ws);

    agg_kernel<<<M_, 256, 0, stream>>>(ws, o_p_fea, p_xyz, out);
}